// Round 1
// baseline (39.251 us; speedup 1.0000x reference)
//
#include <hip/hip_runtime.h>

#define NUM_CLASSES 80
#define OUT_W 13
#define OUT_H 13
#define HW (OUT_W * OUT_H)   // 169
#define NA 5
#define NB 20
#define NBATCH 512

// acc[0]=bbox_sum, acc[1]=iou_sum, acc[2]=cls_sum (raw squared-error sums)
__global__ __launch_bounds__(256)
void yolo_loss_main(const float* __restrict__ bbox_pred,
                    const float* __restrict__ iou_pred,
                    const float* __restrict__ prob_pred,
                    const float* __restrict__ bbox_gt,
                    const int*   __restrict__ cls_gt,
                    const float* __restrict__ anchors,
                    double* __restrict__ acc)
{
    const int b   = blockIdx.x;
    const int tid = threadIdx.x;

    __shared__ float s_anch[NA * 2];
    __shared__ int   s_slot[NB];      // cell*NA + best
    __shared__ int   s_cls[NB];
    __shared__ float s_tgt[NB][4];    // tx, ty, sqrt(gw), sqrt(gh)
    __shared__ int   s_win[NB];       // 1 if this n is the last writer to its slot
    __shared__ int   s_dup[NB];       // 1 if an earlier m has same (slot, class)
    __shared__ double s_red[3][4];    // per-wave partials (256 thr = 4 waves)

    if (tid < NA * 2) s_anch[tid] = anchors[tid];
    __syncthreads();

    // ---- Phase 1: per-GT-box target computation (20 threads) ----
    if (tid < NB) {
        const int n = tid;
        const float* g = bbox_gt + ((size_t)b * NB + n) * 4;
        const float gx = g[0], gy = g[1], gw = g[2], gh = g[3];
        const float rg = gw / gh;
        int best = 0;
        float bd = fabsf(s_anch[0] / s_anch[1] - rg);
        for (int a = 1; a < NA; ++a) {
            float d = fabsf(s_anch[2 * a] / s_anch[2 * a + 1] - rg);
            if (d < bd) { bd = d; best = a; }   // strict <: first min wins (argmin)
        }
        const float cx = gx * (float)OUT_W;
        const float cy = gy * (float)OUT_H;
        const float fx = floorf(cx), fy = floorf(cy);
        const int cell = (int)(fy * (float)OUT_W + fx);
        s_slot[n]   = cell * NA + best;
        s_cls[n]    = cls_gt[(size_t)b * NB + n];
        s_tgt[n][0] = cx - fx;
        s_tgt[n][1] = cy - fy;
        s_tgt[n][2] = sqrtf(gw);
        s_tgt[n][3] = sqrtf(gh);
    }
    __syncthreads();

    if (tid < NB) {
        const int n = tid, slot = s_slot[n];
        int win = 1;
        for (int m = n + 1; m < NB; ++m)
            if (s_slot[m] == slot) { win = 0; break; }   // later write overwrites
        s_win[n] = win;
        int dup = 0;
        for (int m = 0; m < n; ++m)
            if (s_slot[m] == slot && s_cls[m] == s_cls[n]) { dup = 1; break; }
        s_dup[n] = dup;
    }
    __syncthreads();

    double bbox_acc = 0.0, iou_acc = 0.0, cls_acc = 0.0;

    // ---- Phase 2: dense IoU term  0.25 * p^2  over all HW*NA slots ----
    const float* ip = iou_pred + (size_t)b * HW * NA;
    for (int i = tid; i < HW * NA; i += blockDim.x) {
        const float p = ip[i];
        iou_acc += (double)(0.25f * p * p);
    }

    // ---- Phase 3: per-winner bbox + IoU corrections ----
    if (tid < NB && s_win[tid]) {
        const int n = tid;
        const int slot = s_slot[n];
        const int a = slot % NA;
        const float aw = s_anch[2 * a], ah = s_anch[2 * a + 1];
        const float* pp = bbox_pred + (((size_t)b * HW * NA) + slot) * 4;
        const float bp0 = pp[0], bp1 = pp[1];
        const float bp2 = sqrtf(pp[2] * aw);
        const float bp3 = sqrtf(pp[3] * ah);
        const float t0 = s_tgt[n][0], t1 = s_tgt[n][1];
        const float t2 = s_tgt[n][2], t3 = s_tgt[n][3];

        const float d0 = bp0 - t0, d1 = bp1 - t1, d2 = bp2 - t2, d3 = bp3 - t3;
        bbox_acc += (double)(d0 * d0) + (double)(d1 * d1)
                  + (double)(d2 * d2) + (double)(d3 * d3);

        // IoU(bp, tgt), both as (x, y, w, h)
        const float area1 = bp2 * bp3, area2 = t2 * t3;
        float iw = fminf(bp0 + bp2, t0 + t2) - fmaxf(bp0, t0);
        float ih = fminf(bp1 + bp3, t1 + t3) - fmaxf(bp1, t1);
        iw = fmaxf(iw, 0.0f);
        ih = fmaxf(ih, 0.0f);
        const float inter = iw * ih;
        const float iou = inter / (area1 + area2 - inter);

        const float p = ip[slot];
        iou_acc += (double)((p - iou) * (p - iou) - 0.25f * p * p);
    }

    // ---- Phase 4: cls term ----
    // Per unique target slot: sum_c prob_c^2 ; distributed over (n, c) pairs.
    const float* prp = prob_pred + (size_t)b * HW * NA * NUM_CLASSES;
    for (int idx = tid; idx < NB * NUM_CLASSES; idx += blockDim.x) {
        const int n = idx / NUM_CLASSES, c = idx % NUM_CLASSES;
        if (s_win[n]) {
            const float p = prp[(size_t)s_slot[n] * NUM_CLASSES + c];
            cls_acc += (double)(p * p);
        }
    }
    // Per unique (slot, class): (p-1)^2 - p^2 = 1 - 2p
    if (tid < NB && !s_dup[tid]) {
        const int n = tid;
        const float p = prp[(size_t)s_slot[n] * NUM_CLASSES + s_cls[n]];
        cls_acc += (double)(1.0f - 2.0f * p);
    }

    // ---- Block reduction (wave shuffle + LDS) ----
    for (int off = 32; off > 0; off >>= 1) {
        bbox_acc += __shfl_down(bbox_acc, off);
        iou_acc  += __shfl_down(iou_acc,  off);
        cls_acc  += __shfl_down(cls_acc,  off);
    }
    const int wave = tid >> 6, lane = tid & 63;
    if (lane == 0) {
        s_red[0][wave] = bbox_acc;
        s_red[1][wave] = iou_acc;
        s_red[2][wave] = cls_acc;
    }
    __syncthreads();
    if (tid == 0) {
        double bs = 0.0, is = 0.0, cs = 0.0;
        for (int w = 0; w < 4; ++w) { bs += s_red[0][w]; is += s_red[1][w]; cs += s_red[2][w]; }
        atomicAdd(&acc[0], bs);
        atomicAdd(&acc[1], is);
        atomicAdd(&acc[2], cs);
    }
}

__global__ void yolo_loss_final(const double* __restrict__ acc,
                                float* __restrict__ out)
{
    const double N1 = (double)NBATCH * HW * NA * 4;
    const double N2 = (double)NBATCH * HW * NA;
    const double N3 = (double)NBATCH * HW * NA * NUM_CLASSES;
    out[0] = (float)(5.0 * acc[0] / N1 + acc[1] / N2 + acc[2] / N3);
}

extern "C" void kernel_launch(void* const* d_in, const int* in_sizes, int n_in,
                              void* d_out, int out_size, void* d_ws, size_t ws_size,
                              hipStream_t stream)
{
    const float* bbox_pred = (const float*)d_in[0];
    const float* iou_pred  = (const float*)d_in[1];
    const float* prob_pred = (const float*)d_in[2];
    const float* bbox_gt   = (const float*)d_in[3];
    const int*   cls_gt    = (const int*)d_in[4];
    const float* anchors   = (const float*)d_in[5];
    float* out = (float*)d_out;
    double* acc = (double*)d_ws;

    hipMemsetAsync(acc, 0, 3 * sizeof(double), stream);
    yolo_loss_main<<<NBATCH, 256, 0, stream>>>(bbox_pred, iou_pred, prob_pred,
                                               bbox_gt, cls_gt, anchors, acc);
    yolo_loss_final<<<1, 1, 0, stream>>>(acc, out);
}

// Round 2
// 16.392 us; speedup vs baseline: 2.3945x; 2.3945x over previous
//
#include <hip/hip_runtime.h>

#define NUM_CLASSES 80
#define OUT_W 13
#define OUT_H 13
#define HW (OUT_W * OUT_H)   // 169
#define NA 5
#define NB 20
#define NBATCH 512

// Kernel 1: one block per batch. Writes 3 raw partial sums (bbox, iou, cls)
// per block to partials[b*3 + {0,1,2}] -- unconditional stores, no init needed.
__global__ __launch_bounds__(256)
void yolo_loss_main(const float* __restrict__ bbox_pred,
                    const float* __restrict__ iou_pred,
                    const float* __restrict__ prob_pred,
                    const float* __restrict__ bbox_gt,
                    const int*   __restrict__ cls_gt,
                    const float* __restrict__ anchors,
                    double* __restrict__ partials)
{
    const int b   = blockIdx.x;
    const int tid = threadIdx.x;

    __shared__ float s_anch[NA * 2];
    __shared__ int   s_slot[NB];      // cell*NA + best
    __shared__ int   s_cls[NB];
    __shared__ float s_tgt[NB][4];    // tx, ty, sqrt(gw), sqrt(gh)
    __shared__ int   s_win[NB];       // 1 if this n is the last writer to its slot
    __shared__ int   s_dup[NB];       // 1 if an earlier m has same (slot, class)
    __shared__ double s_red[3][4];    // per-wave partials (256 thr = 4 waves)

    if (tid < NA * 2) s_anch[tid] = anchors[tid];
    __syncthreads();

    // ---- Phase 1: per-GT-box target computation (20 threads) ----
    if (tid < NB) {
        const int n = tid;
        const float* g = bbox_gt + ((size_t)b * NB + n) * 4;
        const float gx = g[0], gy = g[1], gw = g[2], gh = g[3];
        const float rg = gw / gh;
        int best = 0;
        float bd = fabsf(s_anch[0] / s_anch[1] - rg);
        for (int a = 1; a < NA; ++a) {
            float d = fabsf(s_anch[2 * a] / s_anch[2 * a + 1] - rg);
            if (d < bd) { bd = d; best = a; }   // strict <: first min wins (argmin)
        }
        const float cx = gx * (float)OUT_W;
        const float cy = gy * (float)OUT_H;
        const float fx = floorf(cx), fy = floorf(cy);
        const int cell = (int)(fy * (float)OUT_W + fx);
        s_slot[n]   = cell * NA + best;
        s_cls[n]    = cls_gt[(size_t)b * NB + n];
        s_tgt[n][0] = cx - fx;
        s_tgt[n][1] = cy - fy;
        s_tgt[n][2] = sqrtf(gw);
        s_tgt[n][3] = sqrtf(gh);
    }
    __syncthreads();

    if (tid < NB) {
        const int n = tid, slot = s_slot[n];
        int win = 1;
        for (int m = n + 1; m < NB; ++m)
            if (s_slot[m] == slot) { win = 0; break; }   // later write overwrites
        s_win[n] = win;
        int dup = 0;
        for (int m = 0; m < n; ++m)
            if (s_slot[m] == slot && s_cls[m] == s_cls[n]) { dup = 1; break; }
        s_dup[n] = dup;
    }
    __syncthreads();

    double bbox_acc = 0.0, iou_acc = 0.0, cls_acc = 0.0;

    // ---- Phase 2: dense IoU term  0.25 * p^2  over all HW*NA slots ----
    const float* ip = iou_pred + (size_t)b * HW * NA;
    for (int i = tid; i < HW * NA; i += blockDim.x) {
        const float p = ip[i];
        iou_acc += (double)(0.25f * p * p);
    }

    // ---- Phase 3: per-winner bbox + IoU corrections ----
    if (tid < NB && s_win[tid]) {
        const int n = tid;
        const int slot = s_slot[n];
        const int a = slot % NA;
        const float aw = s_anch[2 * a], ah = s_anch[2 * a + 1];
        const float* pp = bbox_pred + (((size_t)b * HW * NA) + slot) * 4;
        const float bp0 = pp[0], bp1 = pp[1];
        const float bp2 = sqrtf(pp[2] * aw);
        const float bp3 = sqrtf(pp[3] * ah);
        const float t0 = s_tgt[n][0], t1 = s_tgt[n][1];
        const float t2 = s_tgt[n][2], t3 = s_tgt[n][3];

        const float d0 = bp0 - t0, d1 = bp1 - t1, d2 = bp2 - t2, d3 = bp3 - t3;
        bbox_acc += (double)(d0 * d0) + (double)(d1 * d1)
                  + (double)(d2 * d2) + (double)(d3 * d3);

        // IoU(bp, tgt), both as (x, y, w, h)
        const float area1 = bp2 * bp3, area2 = t2 * t3;
        float iw = fminf(bp0 + bp2, t0 + t2) - fmaxf(bp0, t0);
        float ih = fminf(bp1 + bp3, t1 + t3) - fmaxf(bp1, t1);
        iw = fmaxf(iw, 0.0f);
        ih = fmaxf(ih, 0.0f);
        const float inter = iw * ih;
        const float iou = inter / (area1 + area2 - inter);

        const float p = ip[slot];
        iou_acc += (double)((p - iou) * (p - iou) - 0.25f * p * p);
    }

    // ---- Phase 4: cls term ----
    // Per unique target slot: sum_c prob_c^2 ; distributed over (n, c) pairs.
    const float* prp = prob_pred + (size_t)b * HW * NA * NUM_CLASSES;
    for (int idx = tid; idx < NB * NUM_CLASSES; idx += blockDim.x) {
        const int n = idx / NUM_CLASSES, c = idx % NUM_CLASSES;
        if (s_win[n]) {
            const float p = prp[(size_t)s_slot[n] * NUM_CLASSES + c];
            cls_acc += (double)(p * p);
        }
    }
    // Per unique (slot, class): (p-1)^2 - p^2 = 1 - 2p
    if (tid < NB && !s_dup[tid]) {
        const int n = tid;
        const float p = prp[(size_t)s_slot[n] * NUM_CLASSES + s_cls[n]];
        cls_acc += (double)(1.0f - 2.0f * p);
    }

    // ---- Block reduction (wave shuffle + LDS), then one plain store ----
    for (int off = 32; off > 0; off >>= 1) {
        bbox_acc += __shfl_down(bbox_acc, off);
        iou_acc  += __shfl_down(iou_acc,  off);
        cls_acc  += __shfl_down(cls_acc,  off);
    }
    const int wave = tid >> 6, lane = tid & 63;
    if (lane == 0) {
        s_red[0][wave] = bbox_acc;
        s_red[1][wave] = iou_acc;
        s_red[2][wave] = cls_acc;
    }
    __syncthreads();
    if (tid == 0) {
        double bs = 0.0, is = 0.0, cs = 0.0;
        for (int w = 0; w < 4; ++w) { bs += s_red[0][w]; is += s_red[1][w]; cs += s_red[2][w]; }
        partials[(size_t)b * 3 + 0] = bs;
        partials[(size_t)b * 3 + 1] = is;
        partials[(size_t)b * 3 + 2] = cs;
    }
}

// Kernel 2: one block reduces 512x3 doubles and writes the scalar loss.
__global__ __launch_bounds__(256)
void yolo_loss_final(const double* __restrict__ partials,
                     float* __restrict__ out)
{
    const int tid = threadIdx.x;
    __shared__ double s_red[3][4];

    double bs = 0.0, is = 0.0, cs = 0.0;
    for (int b = tid; b < NBATCH; b += 256) {
        bs += partials[(size_t)b * 3 + 0];
        is += partials[(size_t)b * 3 + 1];
        cs += partials[(size_t)b * 3 + 2];
    }
    for (int off = 32; off > 0; off >>= 1) {
        bs += __shfl_down(bs, off);
        is += __shfl_down(is, off);
        cs += __shfl_down(cs, off);
    }
    const int wave = tid >> 6, lane = tid & 63;
    if (lane == 0) { s_red[0][wave] = bs; s_red[1][wave] = is; s_red[2][wave] = cs; }
    __syncthreads();
    if (tid == 0) {
        double B = 0.0, I = 0.0, C = 0.0;
        for (int w = 0; w < 4; ++w) { B += s_red[0][w]; I += s_red[1][w]; C += s_red[2][w]; }
        const double N1 = (double)NBATCH * HW * NA * 4;
        const double N2 = (double)NBATCH * HW * NA;
        const double N3 = (double)NBATCH * HW * NA * NUM_CLASSES;
        out[0] = (float)(5.0 * B / N1 + I / N2 + C / N3);
    }
}

extern "C" void kernel_launch(void* const* d_in, const int* in_sizes, int n_in,
                              void* d_out, int out_size, void* d_ws, size_t ws_size,
                              hipStream_t stream)
{
    const float* bbox_pred = (const float*)d_in[0];
    const float* iou_pred  = (const float*)d_in[1];
    const float* prob_pred = (const float*)d_in[2];
    const float* bbox_gt   = (const float*)d_in[3];
    const int*   cls_gt    = (const int*)d_in[4];
    const float* anchors   = (const float*)d_in[5];
    float* out = (float*)d_out;
    double* partials = (double*)d_ws;   // 512*3 doubles = 12 KiB

    yolo_loss_main<<<NBATCH, 256, 0, stream>>>(bbox_pred, iou_pred, prob_pred,
                                               bbox_gt, cls_gt, anchors, partials);
    yolo_loss_final<<<1, 256, 0, stream>>>(partials, out);
}